// Round 2
// baseline (658.822 us; speedup 1.0000x reference)
//
#include <hip/hip_runtime.h>
#include <hip/hip_bf16.h>

#define B_  2
#define S_  4096
#define D_  768
#define H_  12
#define DH_ 64

typedef __bf16 bf16x8 __attribute__((ext_vector_type(8)));
typedef short  svec8  __attribute__((ext_vector_type(8)));
typedef float  fvec4  __attribute__((ext_vector_type(4)));
typedef unsigned short ushort_t;

__device__ __forceinline__ ushort_t f2bf(float f){
    unsigned u = __builtin_bit_cast(unsigned, f);
    unsigned r = (u + 0x7fffu + ((u >> 16) & 1u)) >> 16;
    return (ushort_t)r;
}

__device__ __forceinline__ fvec4 mfma16(svec8 a, svec8 b, fvec4 c){
    return __builtin_amdgcn_mfma_f32_16x16x32_bf16(
        __builtin_bit_cast(bf16x8, a), __builtin_bit_cast(bf16x8, b), c, 0, 0, 0);
}

// ---------------- QKV projection: per-head GEMM [8192x768]*[768x64] ----------------
// fp32 inputs -> bf16 LDS tiles -> MFMA -> bf16 Q/K/V in workspace.
// grid: (64 m-tiles, 12 heads, 3 weights), block 256 threads (4 waves)
// block tile: M=128, N=64 (one head), BK=64
__global__ __launch_bounds__(256) void qkv_proj(
    const float* __restrict__ X,
    const float* __restrict__ Wq, const float* __restrict__ Wk, const float* __restrict__ Wv,
    ushort_t* __restrict__ Qb, ushort_t* __restrict__ Kb, ushort_t* __restrict__ Vb)
{
    const int m0 = blockIdx.x * 128;
    const int h  = blockIdx.y;
    const int wt = blockIdx.z;
    const float* W    = (wt == 0) ? Wq : (wt == 1) ? Wk : Wv;
    ushort_t*    Out  = (wt == 0) ? Qb : (wt == 1) ? Kb : Vb;
    const float* Wh   = W + (size_t)h * (D_ * DH_);

    __shared__ ushort_t Xs[128 * 72];   // padded stride 72 (2-way bank alias = free)
    __shared__ ushort_t Wt[64 * 72];    // W tile transposed: Wt[n][k]

    const int tid  = threadIdx.x;
    const int w    = tid >> 6;
    const int lane = tid & 63;
    const int quad = lane >> 4;
    const int l15  = lane & 15;

    fvec4 acc[2][4];
    #pragma unroll
    for (int i = 0; i < 2; i++)
        #pragma unroll
        for (int j = 0; j < 4; j++) acc[i][j] = (fvec4){0.f, 0.f, 0.f, 0.f};

    for (int k0 = 0; k0 < D_; k0 += 64) {
        // stage X tile 128x64: float4 loads, convert to bf16
        #pragma unroll
        for (int i = 0; i < 8; i++) {
            int v = tid + 256 * i;
            int r = v >> 4, c = (v & 15) * 4;
            float4 d = *(const float4*)(X + (size_t)(m0 + r) * D_ + k0 + c);
            ushort_t* p = Xs + r * 72 + c;
            p[0] = f2bf(d.x); p[1] = f2bf(d.y); p[2] = f2bf(d.z); p[3] = f2bf(d.w);
        }
        // stage W tile 64x64, transposed into Wt[n][k]
        #pragma unroll
        for (int i = 0; i < 4; i++) {
            int v = tid + 256 * i;
            int r = v >> 4, c = (v & 15) * 4;   // r = k row, c = n col base
            float4 d = *(const float4*)(Wh + (size_t)(k0 + r) * DH_ + c);
            Wt[(c + 0) * 72 + r] = f2bf(d.x);
            Wt[(c + 1) * 72 + r] = f2bf(d.y);
            Wt[(c + 2) * 72 + r] = f2bf(d.z);
            Wt[(c + 3) * 72 + r] = f2bf(d.w);
        }
        __syncthreads();

        #pragma unroll
        for (int ks = 0; ks < 2; ks++) {
            svec8 a0 = *(const svec8*)(Xs + (32 * w + l15) * 72 + ks * 32 + quad * 8);
            svec8 a1 = *(const svec8*)(Xs + (32 * w + 16 + l15) * 72 + ks * 32 + quad * 8);
            #pragma unroll
            for (int ns = 0; ns < 4; ns++) {
                svec8 b = *(const svec8*)(Wt + (ns * 16 + l15) * 72 + ks * 32 + quad * 8);
                acc[0][ns] = mfma16(a0, b, acc[0][ns]);
                acc[1][ns] = mfma16(a1, b, acc[1][ns]);
            }
        }
        __syncthreads();
    }

    // epilogue: D layout d[r] = D[quad*4+r][l15]; store bf16 to workspace
    #pragma unroll
    for (int ms = 0; ms < 2; ms++)
        #pragma unroll
        for (int ns = 0; ns < 4; ns++)
            #pragma unroll
            for (int r = 0; r < 4; r++) {
                int row = m0 + 32 * w + ms * 16 + quad * 4 + r;
                int col = h * DH_ + ns * 16 + l15;
                Out[(size_t)row * D_ + col] = f2bf(acc[ms][ns][r]);
            }
}

// ---------------- causal flash attention (bf16 in, fp32 out) ----------------
// grid: (64 q-tiles, 12 heads, 2 batches), block 256 (4 waves); wave owns 16 q-rows
__global__ __launch_bounds__(256) void attn(
    const ushort_t* __restrict__ Qb, const ushort_t* __restrict__ Kb,
    const ushort_t* __restrict__ Vb, float* __restrict__ Out)
{
    const int qt = gridDim.x - 1 - blockIdx.x;   // long blocks first
    const int h  = blockIdx.y;
    const int b  = blockIdx.z;
    const int q0 = qt * 64;

    const int tid  = threadIdx.x;
    const int w    = tid >> 6;
    const int lane = tid & 63;
    const int quad = lane >> 4;
    const int l15  = lane & 15;

    __shared__ ushort_t Ks[64 * 72];      // K tile natural [kk][e]
    __shared__ ushort_t Vt[64 * 72];      // V tile transposed [e][kk]
    __shared__ ushort_t Ps[4 * 16 * 72];  // per-wave P staging [16 rows][64 cols]
    ushort_t* Pw = Ps + w * 16 * 72;

    const size_t hb = (size_t)b * S_ * D_ + (size_t)h * DH_;

    // Q fragments (A-operand), reused across all K tiles
    svec8 aq[2];
    {
        const ushort_t* qrow = Qb + hb + (size_t)(q0 + 16 * w + l15) * D_;
        aq[0] = *(const svec8*)(qrow + quad * 8);
        aq[1] = *(const svec8*)(qrow + 32 + quad * 8);
    }

    float m_i[4], l_i[4];
    fvec4 acc[4];
    #pragma unroll
    for (int r = 0; r < 4; r++) { m_i[r] = -INFINITY; l_i[r] = 0.f; }
    #pragma unroll
    for (int n = 0; n < 4; n++) acc[n] = (fvec4){0.f, 0.f, 0.f, 0.f};

    const float sc = 0.125f * 1.44269504088896341f;  // 1/sqrt(64) * log2(e)

    for (int kt = 0; kt <= qt; ++kt) {
        // stage K (natural) and V (transposed) from bf16 workspace
        #pragma unroll
        for (int i = 0; i < 2; i++) {
            int v = tid + 256 * i;
            int r = v >> 3, c = (v & 7) * 8;
            const size_t g = hb + (size_t)(kt * 64 + r) * D_ + c;
            svec8 kd = *(const svec8*)(Kb + g);
            *(svec8*)(Ks + r * 72 + c) = kd;
            svec8 vd = *(const svec8*)(Vb + g);
            #pragma unroll
            for (int j = 0; j < 8; j++) Vt[(c + j) * 72 + r] = ((ushort_t*)&vd)[j];
        }
        __syncthreads();

        // S = Q K^T : wave rows [16w,16w+16), cols 0..63
        fvec4 s[4];
        #pragma unroll
        for (int n = 0; n < 4; n++) s[n] = (fvec4){0.f, 0.f, 0.f, 0.f};
        #pragma unroll
        for (int ks = 0; ks < 2; ks++)
            #pragma unroll
            for (int n = 0; n < 4; n++) {
                svec8 bk = *(const svec8*)(Ks + (n * 16 + l15) * 72 + ks * 32 + quad * 8);
                s[n] = mfma16(aq[ks], bk, s[n]);
            }

        // scale (to log2 domain) + causal mask on the diagonal tile
        const bool diag = (kt == qt);
        #pragma unroll
        for (int n = 0; n < 4; n++)
            #pragma unroll
            for (int r = 0; r < 4; r++) {
                float v = s[n][r] * sc;
                if (diag) {
                    int col = kt * 64 + n * 16 + l15;
                    int row = q0 + 16 * w + quad * 4 + r;
                    if (col > row) v = -INFINITY;
                }
                s[n][r] = v;
            }

        // row max (reduce across the 16 lanes sharing a quad)
        float alpha[4];
        #pragma unroll
        for (int r = 0; r < 4; r++) {
            float v = fmaxf(fmaxf(s[0][r], s[1][r]), fmaxf(s[2][r], s[3][r]));
            v = fmaxf(v, __shfl_xor(v, 1, 16));
            v = fmaxf(v, __shfl_xor(v, 2, 16));
            v = fmaxf(v, __shfl_xor(v, 4, 16));
            v = fmaxf(v, __shfl_xor(v, 8, 16));
            float mn = fmaxf(m_i[r], v);
            alpha[r] = exp2f(m_i[r] - mn);
            m_i[r] = mn;
        }

        // P = exp2(s - m), row sums, stage P to wave-private LDS
        float rs[4] = {0.f, 0.f, 0.f, 0.f};
        #pragma unroll
        for (int n = 0; n < 4; n++)
            #pragma unroll
            for (int r = 0; r < 4; r++) {
                float p = exp2f(s[n][r] - m_i[r]);
                rs[r] += p;
                Pw[(quad * 4 + r) * 72 + n * 16 + l15] = f2bf(p);
            }
        #pragma unroll
        for (int r = 0; r < 4; r++) {
            float v = rs[r];
            v += __shfl_xor(v, 1, 16);
            v += __shfl_xor(v, 2, 16);
            v += __shfl_xor(v, 4, 16);
            v += __shfl_xor(v, 8, 16);
            l_i[r] = l_i[r] * alpha[r] + v;
        }
        #pragma unroll
        for (int n = 0; n < 4; n++)
            #pragma unroll
            for (int r = 0; r < 4; r++) acc[n][r] *= alpha[r];

        __syncthreads();  // order P writes before fragment reads

        // O += P V
        #pragma unroll
        for (int ks = 0; ks < 2; ks++) {
            svec8 ap = *(const svec8*)(Pw + l15 * 72 + ks * 32 + quad * 8);
            #pragma unroll
            for (int n = 0; n < 4; n++) {
                svec8 bv = *(const svec8*)(Vt + (n * 16 + l15) * 72 + ks * 32 + quad * 8);
                acc[n] = mfma16(ap, bv, acc[n]);
            }
        }
        __syncthreads();  // protect Ks/Vt before next staging
    }

    // epilogue: O = acc / l, fp32 head-concat layout [B,S,H*DH]
    #pragma unroll
    for (int n = 0; n < 4; n++)
        #pragma unroll
        for (int r = 0; r < 4; r++) {
            int row = q0 + 16 * w + quad * 4 + r;
            int col = h * DH_ + n * 16 + l15;
            Out[((size_t)b * S_ + row) * D_ + col] = acc[n][r] / l_i[r];
        }
}

extern "C" void kernel_launch(void* const* d_in, const int* in_sizes, int n_in,
                              void* d_out, int out_size, void* d_ws, size_t ws_size,
                              hipStream_t stream)
{
    const float* X  = (const float*)d_in[0];
    const float* Wq = (const float*)d_in[1];
    const float* Wk = (const float*)d_in[2];
    const float* Wv = (const float*)d_in[3];

    ushort_t* Qb = (ushort_t*)d_ws;
    ushort_t* Kb = Qb + (size_t)B_ * S_ * D_;
    ushort_t* Vb = Kb + (size_t)B_ * S_ * D_;
    float* Out = (float*)d_out;

    dim3 g1(64, H_, 3), blk(256);
    qkv_proj<<<g1, blk, 0, stream>>>(X, Wq, Wk, Wv, Qb, Kb, Vb);

    dim3 g2(S_ / 64, H_, B_);
    attn<<<g2, blk, 0, stream>>>(Qb, Kb, Vb, Out);
}

// Round 3
// 453.594 us; speedup vs baseline: 1.4524x; 1.4524x over previous
//
#include <hip/hip_runtime.h>
#include <hip/hip_bf16.h>

#define B_  2
#define S_  4096
#define D_  768
#define H_  12
#define DH_ 64

typedef __bf16 bf16x8 __attribute__((ext_vector_type(8)));
typedef short  svec8  __attribute__((ext_vector_type(8)));
typedef float  fvec4  __attribute__((ext_vector_type(4)));
typedef unsigned short ushort_t;

__device__ __forceinline__ ushort_t f2bf(float f){
    unsigned u = __builtin_bit_cast(unsigned, f);
    unsigned r = (u + 0x7fffu + ((u >> 16) & 1u)) >> 16;
    return (ushort_t)r;
}

__device__ __forceinline__ fvec4 mfma16(svec8 a, svec8 b, fvec4 c){
    return __builtin_amdgcn_mfma_f32_16x16x32_bf16(
        __builtin_bit_cast(bf16x8, a), __builtin_bit_cast(bf16x8, b), c, 0, 0, 0);
}

// ---------------- QKV projection ----------------
// fp32 X,W -> bf16 MFMA -> Q,K bf16 natural [8192][768]; V written TRANSPOSED
// per head: Vg[(h*64+e)][8192] so attention can stage it vectorized.
// grid: (64 m-tiles, 12 heads, 3 weights), block 256 (4 waves). M=128,N=64,BK=64.
__global__ __launch_bounds__(256) void qkv_proj(
    const float* __restrict__ X,
    const float* __restrict__ Wq, const float* __restrict__ Wk, const float* __restrict__ Wv,
    ushort_t* __restrict__ Qb, ushort_t* __restrict__ Kb, ushort_t* __restrict__ Vg)
{
    const int m0 = blockIdx.x * 128;
    const int h  = blockIdx.y;
    const int wt = blockIdx.z;
    const float* W  = (wt == 0) ? Wq : (wt == 1) ? Wk : Wv;
    const float* Wh = W + (size_t)h * (D_ * DH_);

    // smem: Xs 128x72 shorts (9216) | Wt 64x64 swizzled (4096). XsT overlays Xs.
    __shared__ ushort_t smem[128 * 72 + 64 * 64];
    ushort_t* Xs  = smem;
    ushort_t* Wts = smem + 128 * 72;
    ushort_t* XsT = smem;              // 64 x 136 (8704 shorts) overlay, used after K-loop

    const int tid  = threadIdx.x;
    const int w    = tid >> 6;
    const int lane = tid & 63;
    const int quad = lane >> 4;
    const int l15  = lane & 15;

    fvec4 acc[2][4];
    #pragma unroll
    for (int i = 0; i < 2; i++)
        #pragma unroll
        for (int j = 0; j < 4; j++) acc[i][j] = (fvec4){0.f, 0.f, 0.f, 0.f};

    for (int k0 = 0; k0 < D_; k0 += 64) {
        // X tile 128x64: 8 floats/thread -> one b128 LDS write (balanced banks)
        #pragma unroll
        for (int i = 0; i < 4; i++) {
            int v = tid + 256 * i;
            int r = v >> 3, c = (v & 7) * 8;
            const float* src = X + (size_t)(m0 + r) * D_ + k0 + c;
            float4 d0 = *(const float4*)(src);
            float4 d1 = *(const float4*)(src + 4);
            svec8 pk;
            pk[0] = (short)f2bf(d0.x); pk[1] = (short)f2bf(d0.y);
            pk[2] = (short)f2bf(d0.z); pk[3] = (short)f2bf(d0.w);
            pk[4] = (short)f2bf(d1.x); pk[5] = (short)f2bf(d1.y);
            pk[6] = (short)f2bf(d1.z); pk[7] = (short)f2bf(d1.w);
            *(svec8*)(Xs + r * 72 + c) = pk;
        }
        // W tile 64x64 transposed into XOR-swizzled layout:
        // Wt(n,k) at n*64 + (((k>>3) ^ ((n>>2)&7))<<3) + (k&7)
        #pragma unroll
        for (int i = 0; i < 4; i++) {
            int v = tid + 256 * i;
            int k = v >> 4, t = v & 15;
            float4 d = *(const float4*)(Wh + (size_t)(k0 + k) * DH_ + t * 4);
            #pragma unroll
            for (int j = 0; j < 4; j++) {
                int n = t * 4 + j;
                int addr = n * 64 + ((((k >> 3) ^ (t & 7))) << 3) + (k & 7);
                Wts[addr] = f2bf(j == 0 ? d.x : j == 1 ? d.y : j == 2 ? d.z : d.w);
            }
        }
        __syncthreads();

        #pragma unroll
        for (int ks = 0; ks < 2; ks++) {
            svec8 a0 = *(const svec8*)(Xs + (32 * w + l15) * 72 + ks * 32 + quad * 8);
            svec8 a1 = *(const svec8*)(Xs + (32 * w + 16 + l15) * 72 + ks * 32 + quad * 8);
            #pragma unroll
            for (int ns = 0; ns < 4; ns++) {
                int n = ns * 16 + l15;
                int swz = (ks * 4 + quad) ^ ((n >> 2) & 7);
                svec8 b = *(const svec8*)(Wts + n * 64 + swz * 8);
                acc[0][ns] = mfma16(a0, b, acc[0][ns]);
                acc[1][ns] = mfma16(a1, b, acc[1][ns]);
            }
        }
        __syncthreads();
    }

    if (wt != 2) {
        ushort_t* Out = (wt == 0) ? Qb : Kb;
        #pragma unroll
        for (int ms = 0; ms < 2; ms++)
            #pragma unroll
            for (int ns = 0; ns < 4; ns++)
                #pragma unroll
                for (int r = 0; r < 4; r++) {
                    int row = m0 + 32 * w + ms * 16 + quad * 4 + r;
                    int col = h * DH_ + ns * 16 + l15;
                    Out[(size_t)row * D_ + col] = f2bf(acc[ms][ns][r]);
                }
    } else {
        // V: transpose through LDS, write Vg[(h*64+e)][8192] coalesced
        #pragma unroll
        for (int ms = 0; ms < 2; ms++)
            #pragma unroll
            for (int ns = 0; ns < 4; ns++)
                #pragma unroll
                for (int r = 0; r < 4; r++) {
                    int sl = 32 * w + ms * 16 + quad * 4 + r;
                    int e  = ns * 16 + l15;
                    XsT[e * 136 + sl] = f2bf(acc[ms][ns][r]);
                }
        __syncthreads();
        #pragma unroll
        for (int i = 0; i < 4; i++) {
            int v = tid + 256 * i;
            int e = v >> 4, s0 = (v & 15) * 8;
            svec8 d = *(const svec8*)(XsT + e * 136 + s0);
            *(svec8*)(Vg + (size_t)(h * DH_ + e) * (B_ * S_) + m0 + s0) = d;
        }
    }
}

// ---------------- causal flash attention ----------------
// K natural [s][768], V^T [h*64+e][8192]; double-buffered LDS, 1 barrier/iter.
// grid: (64 q-tiles, 12 heads, 2 batches), block 256 (4 waves); wave owns 16 q-rows.
__global__ __launch_bounds__(256) void attn(
    const ushort_t* __restrict__ Qb, const ushort_t* __restrict__ Kb,
    const ushort_t* __restrict__ Vg, float* __restrict__ Out)
{
    const int qt = gridDim.x - 1 - blockIdx.x;   // long blocks first
    const int h  = blockIdx.y;
    const int b  = blockIdx.z;
    const int q0 = qt * 64;

    const int tid  = threadIdx.x;
    const int w    = tid >> 6;
    const int lane = tid & 63;
    const int quad = lane >> 4;
    const int l15  = lane & 15;

    __shared__ ushort_t Ks[2 * 64 * 72];
    __shared__ ushort_t Vt[2 * 64 * 72];
    __shared__ ushort_t Ps[4 * 16 * 72];
    ushort_t* Pw = Ps + w * 16 * 72;

    const size_t hb = (size_t)b * S_ * D_ + (size_t)h * DH_;
    const ushort_t* Vh = Vg + (size_t)h * DH_ * (B_ * S_) + (size_t)b * S_;

    const int sr = tid >> 3;          // 0..31 (+32 per task)
    const int sc = (tid & 7) * 8;

    // Q fragments (A-operand), reused across all K tiles
    svec8 aq[2];
    {
        const ushort_t* qrow = Qb + hb + (size_t)(q0 + 16 * w + l15) * D_;
        aq[0] = *(const svec8*)(qrow + quad * 8);
        aq[1] = *(const svec8*)(qrow + 32 + quad * 8);
    }

    float m_i[4], l_i[4];
    fvec4 acc[4];
    #pragma unroll
    for (int r = 0; r < 4; r++) { m_i[r] = -INFINITY; l_i[r] = 0.f; }
    #pragma unroll
    for (int n = 0; n < 4; n++) acc[n] = (fvec4){0.f, 0.f, 0.f, 0.f};

    const float sc_f = 0.125f * 1.44269504088896341f;  // 1/sqrt(64) * log2(e)

    // prologue: stage tile 0 into buffer 0
    svec8 kd[2], vd[2];
    #pragma unroll
    for (int i = 0; i < 2; i++) {
        int r = sr + 32 * i;
        kd[i] = *(const svec8*)(Kb + hb + (size_t)r * D_ + sc);
        vd[i] = *(const svec8*)(Vh + (size_t)r * (B_ * S_) + sc);
    }
    #pragma unroll
    for (int i = 0; i < 2; i++) {
        int r = sr + 32 * i;
        *(svec8*)(Ks + r * 72 + sc) = kd[i];
        *(svec8*)(Vt + r * 72 + sc) = vd[i];
    }

    for (int kt = 0; kt <= qt; ++kt) {
        __syncthreads();   // buf[kt&1] ready for reads; buf[kt&1 ^1] free for writes
        const int cur = (kt & 1) * (64 * 72);

        // prefetch next tile into registers (in flight during compute)
        if (kt < qt) {
            #pragma unroll
            for (int i = 0; i < 2; i++) {
                int r = sr + 32 * i;
                kd[i] = *(const svec8*)(Kb + hb + (size_t)((kt + 1) * 64 + r) * D_ + sc);
                vd[i] = *(const svec8*)(Vh + (size_t)r * (B_ * S_) + (kt + 1) * 64 + sc);
            }
        }

        // S = Q K^T
        fvec4 s[4];
        #pragma unroll
        for (int n = 0; n < 4; n++) s[n] = (fvec4){0.f, 0.f, 0.f, 0.f};
        #pragma unroll
        for (int ks = 0; ks < 2; ks++)
            #pragma unroll
            for (int n = 0; n < 4; n++) {
                svec8 bk = *(const svec8*)(Ks + cur + (n * 16 + l15) * 72 + ks * 32 + quad * 8);
                s[n] = mfma16(aq[ks], bk, s[n]);
            }

        // scale + causal mask on diagonal tile
        const bool diag = (kt == qt);
        #pragma unroll
        for (int n = 0; n < 4; n++)
            #pragma unroll
            for (int r = 0; r < 4; r++) {
                float v = s[n][r] * sc_f;
                if (diag) {
                    int col = n * 16 + l15;
                    int row = 16 * w + quad * 4 + r;
                    if (col > row) v = -INFINITY;
                }
                s[n][r] = v;
            }

        // row max across the 16 lanes of the quad-row
        float alpha[4];
        #pragma unroll
        for (int r = 0; r < 4; r++) {
            float v = fmaxf(fmaxf(s[0][r], s[1][r]), fmaxf(s[2][r], s[3][r]));
            v = fmaxf(v, __shfl_xor(v, 1, 16));
            v = fmaxf(v, __shfl_xor(v, 2, 16));
            v = fmaxf(v, __shfl_xor(v, 4, 16));
            v = fmaxf(v, __shfl_xor(v, 8, 16));
            float mn = fmaxf(m_i[r], v);
            alpha[r] = exp2f(m_i[r] - mn);
            m_i[r] = mn;
        }

        // P = exp2(s-m); stage to wave-private LDS (no block barrier needed)
        float rs[4] = {0.f, 0.f, 0.f, 0.f};
        #pragma unroll
        for (int n = 0; n < 4; n++)
            #pragma unroll
            for (int r = 0; r < 4; r++) {
                float p = exp2f(s[n][r] - m_i[r]);
                rs[r] += p;
                Pw[(quad * 4 + r) * 72 + n * 16 + l15] = f2bf(p);
            }
        #pragma unroll
        for (int r = 0; r < 4; r++) {
            float v = rs[r];
            v += __shfl_xor(v, 1, 16);
            v += __shfl_xor(v, 2, 16);
            v += __shfl_xor(v, 4, 16);
            v += __shfl_xor(v, 8, 16);
            l_i[r] = l_i[r] * alpha[r] + v;
        }
        #pragma unroll
        for (int n = 0; n < 4; n++)
            #pragma unroll
            for (int r = 0; r < 4; r++) acc[n][r] *= alpha[r];

        // wave-private visibility: drain LDS queue (DS ops complete in order)
        asm volatile("s_waitcnt lgkmcnt(0)" ::: "memory");

        // O += P V
        #pragma unroll
        for (int ks = 0; ks < 2; ks++) {
            svec8 ap = *(const svec8*)(Pw + l15 * 72 + ks * 32 + quad * 8);
            #pragma unroll
            for (int n = 0; n < 4; n++) {
                svec8 bv = *(const svec8*)(Vt + cur + (n * 16 + l15) * 72 + ks * 32 + quad * 8);
                acc[n] = mfma16(ap, bv, acc[n]);
            }
        }

        // write prefetched tile into the other buffer (readers finished pre-barrier)
        if (kt < qt) {
            const int nxt = cur ^ (64 * 72);
            #pragma unroll
            for (int i = 0; i < 2; i++) {
                int r = sr + 32 * i;
                *(svec8*)(Ks + nxt + r * 72 + sc) = kd[i];
                *(svec8*)(Vt + nxt + r * 72 + sc) = vd[i];
            }
        }
    }

    // epilogue: O = acc / l, fp32 [B,S,H*DH]
    #pragma unroll
    for (int n = 0; n < 4; n++)
        #pragma unroll
        for (int r = 0; r < 4; r++) {
            int row = q0 + 16 * w + quad * 4 + r;
            int col = h * DH_ + n * 16 + l15;
            Out[((size_t)b * S_ + row) * D_ + col] = acc[n][r] / l_i[r];
        }
}

extern "C" void kernel_launch(void* const* d_in, const int* in_sizes, int n_in,
                              void* d_out, int out_size, void* d_ws, size_t ws_size,
                              hipStream_t stream)
{
    const float* X  = (const float*)d_in[0];
    const float* Wq = (const float*)d_in[1];
    const float* Wk = (const float*)d_in[2];
    const float* Wv = (const float*)d_in[3];

    ushort_t* Qb = (ushort_t*)d_ws;
    ushort_t* Kb = Qb + (size_t)B_ * S_ * D_;
    ushort_t* Vg = Kb + (size_t)B_ * S_ * D_;   // V transposed: [h*64+e][B_*S_]
    float* Out = (float*)d_out;

    dim3 g1(64, H_, 3), blk(256);
    qkv_proj<<<g1, blk, 0, stream>>>(X, Wq, Wk, Wv, Qb, Kb, Vg);

    dim3 g2(S_ / 64, H_, B_);
    attn<<<g2, blk, 0, stream>>>(Qb, Kb, Vg, Out);
}